// Round 1
// baseline (276.913 us; speedup 1.0000x reference)
//
#include <hip/hip_runtime.h>

#define H_ 512
#define W_ 512
#define B_ 8
#define C_ 19
#define HW_ (H_ * W_)            // 262144
#define NPIX (B_ * HW_)          // 2097152
#define NGROUPS (NPIX / 4)       // 524288

#define MAIN_BLOCKS 512
#define MAIN_THREADS 256
#define PSTRIDE 64               // floats per block partial record
#define DIFF_ELEMS ((H_ - 2) * W_)   // 261120
#define DIFF_BYTES_PAD 262144    // padded, 16B-aligned offset for partials

#define NVALS 61                 // 4 scalars + 19 sum_probs + 19 inter + 19 count

__device__ __forceinline__ float wred(float v) {
    v += __shfl_down(v, 32);
    v += __shfl_down(v, 16);
    v += __shfl_down(v, 8);
    v += __shfl_down(v, 4);
    v += __shfl_down(v, 2);
    v += __shfl_down(v, 1);
    return v;
}

// diff[h2*W + w] = any over batch of (vertical 3-run at rows h2..h2+2, col w is non-constant)
__global__ void diff_kernel(const int* __restrict__ tgt, unsigned char* __restrict__ diff) {
    int idx = blockIdx.x * blockDim.x + threadIdx.x;
    if (idx >= DIFF_ELEMS) return;
    int flag = 0;
    const int* p = tgt + idx;    // t[b, h2, w] = tgt[b*HW + idx]
#pragma unroll
    for (int b = 0; b < B_; ++b) {
        int t0 = p[0];
        int t1 = p[W_];
        int t2 = p[2 * W_];
        flag |= (int)(t0 != t1) | (int)(t1 != t2);
        p += HW_;
    }
    diff[idx] = (unsigned char)flag;
}

__global__ __launch_bounds__(MAIN_THREADS, 2) void main_kernel(
    const float* __restrict__ x, const int* __restrict__ tgt,
    const unsigned char* __restrict__ diff, float* __restrict__ partials)
{
    float acc[NVALS];
#pragma unroll
    for (int k = 0; k < NVALS; ++k) acc[k] = 0.f;

    const int tid = threadIdx.x;
    const int stride = MAIN_BLOCKS * MAIN_THREADS;   // 131072 threads

    for (int g = blockIdx.x * MAIN_THREADS + tid; g < NGROUPS; g += stride) {
        const int p0 = g << 2;               // first pixel of the float4 group
        const int b  = p0 >> 18;             // HW = 2^18
        const int hw = p0 & (HW_ - 1);
        const int h  = hw >> 9;              // W = 2^9
        const int w0 = hw & (W_ - 1);

        const float4* xp = (const float4*)(x + (size_t)b * (C_ * HW_) + hw);
        float v[C_][4];
#pragma unroll
        for (int c = 0; c < C_; ++c) {
            float4 t = xp[c * (HW_ / 4)];    // channel stride HW/4 float4s
            v[c][0] = t.x; v[c][1] = t.y; v[c][2] = t.z; v[c][3] = t.w;
        }
        const int4 t4 = ((const int4*)tgt)[g];
        const int tArr[4] = {t4.x, t4.y, t4.z, t4.w};

        const bool hOK = (h >= 1) && (h <= H_ - 2);
        const int drow = (h - 1) << 9;

#pragma unroll
        for (int i = 0; i < 4; ++i) {
            const int t = tArr[i];
            float m = v[0][i];
#pragma unroll
            for (int c = 1; c < C_; ++c) m = fmaxf(m, v[c][i]);
            float se = 0.f, sx = 0.f, xt = 0.f, et = 0.f;
#pragma unroll
            for (int c = 0; c < C_; ++c) {
                const float xv = v[c][i];
                const float e = __expf(xv - m);
                se += e;
                sx += xv;
                const bool sel = (c == t);
                xt = sel ? xv : xt;
                et = sel ? e : et;
                v[c][i] = e;                  // reuse register for probs pass
            }
            const float invse = 1.f / se;
            const float lsum = __logf(se);
            const float nll = lsum - (xt - m);        // -(x_t - lse)
            const float pt = et * invse;
            const float omp = 1.f - pt;
            acc[0] += omp * omp * nll;                // focal
            acc[1] += nll;                            // sum nll
            acc[2] += (lsum + m) - sx * (1.f / C_);   // smooth = lse - mean_c x
            const int w = w0 + i;
            float bf = 0.f;
            if (hOK && w >= 1 && w <= W_ - 2) {
                const int dbase = drow + (w - 1);
                const unsigned d = (unsigned)diff[dbase] | (unsigned)diff[dbase + 1]
                                 | (unsigned)diff[dbase + 2];
                bf = d ? 1.f : 0.f;
            }
            acc[3] += nll * bf;                       // sum nll*bmap
#pragma unroll
            for (int c = 0; c < C_; ++c) {
                acc[4 + c] += v[c][i] * invse;        // sum probs[c]
                const bool sel = (c == t);
                acc[23 + c] += sel ? pt : 0.f;        // inter[c]
                acc[42 + c] += sel ? 1.f : 0.f;       // count[c]
            }
        }
    }

    // block reduction: wave shuffle -> LDS -> per-block partial record
    __shared__ float red[MAIN_THREADS / 64][NVALS];
    const int lane = tid & 63;
    const int wid = tid >> 6;
#pragma unroll
    for (int k = 0; k < NVALS; ++k) {
        const float r = wred(acc[k]);
        if (lane == 0) red[wid][k] = r;
    }
    __syncthreads();
    if (tid < NVALS) {
        float s = 0.f;
#pragma unroll
        for (int wv = 0; wv < MAIN_THREADS / 64; ++wv) s += red[wv][tid];
        partials[blockIdx.x * PSTRIDE + tid] = s;
    }
}

__global__ void finalize_kernel(const float* __restrict__ partials, float* __restrict__ out) {
    __shared__ double grp[4][NVALS];
    const int tid = threadIdx.x;
    const int lane = tid & 63;
    const int g = tid >> 6;
    if (lane < NVALS) {
        double s = 0.0;
        for (int b = g; b < MAIN_BLOCKS; b += 4)
            s += (double)partials[b * PSTRIDE + lane];
        grp[g][lane] = s;
    }
    __syncthreads();
    if (tid == 0) {
        double sums[NVALS];
        for (int k = 0; k < NVALS; ++k)
            sums[k] = grp[0][k] + grp[1][k] + grp[2][k] + grp[3][k];
        const double Np = (double)NPIX;
        const double focal = sums[0] / Np;
        const double ce = (0.9 * sums[1] + 0.1 * sums[2]) / Np;         // label smooth 0.1
        const double boundary = (sums[1] + 0.5 * sums[3]) / Np;          // 1 + 0.5*bmap
        double dice = 0.0;
        for (int c = 0; c < C_; ++c) {
            const double I2 = 2.0 * sums[23 + c] + 1e-5;
            const double D = sums[4 + c] + sums[42 + c] + 1e-5;
            dice += 1.0 - I2 / D;
        }
        dice /= (double)C_;
        const double total = focal + dice + ce + boundary;
        out[0] = (float)focal;
        out[1] = (float)dice;
        out[2] = (float)ce;
        out[3] = (float)boundary;
        out[4] = (float)total;
    }
}

extern "C" void kernel_launch(void* const* d_in, const int* in_sizes, int n_in,
                              void* d_out, int out_size, void* d_ws, size_t ws_size,
                              hipStream_t stream) {
    const float* x = (const float*)d_in[0];        // [8,19,512,512] f32
    const int* tgt = (const int*)d_in[1];          // [8,512,512] i32
    float* out = (float*)d_out;                    // 5 f32
    unsigned char* diff = (unsigned char*)d_ws;
    float* partials = (float*)((char*)d_ws + DIFF_BYTES_PAD);

    diff_kernel<<<(DIFF_ELEMS + 255) / 256, 256, 0, stream>>>(tgt, diff);
    main_kernel<<<MAIN_BLOCKS, MAIN_THREADS, 0, stream>>>(x, tgt, diff, partials);
    finalize_kernel<<<1, 256, 0, stream>>>(partials, out);
}